// Round 1
// baseline (271.110 us; speedup 1.0000x reference)
//
#include <hip/hip_runtime.h>
#include <math.h>

// SpectralTokenizer: 262144 rows x 100 fp32 -> per row 5 frames (hop 8, len 64),
// Hann window, rfft-64, log1p(|.|), freq-major flatten -> 165 fp32 per row.

#define ROWS_PER_BLOCK 64
#define BLOCK_THREADS (ROWS_PER_BLOCK * 5)   // 320 = 5 waves
#define ROW_LEN 100
#define OUT_PER_ROW 165                      // 33 freq * 5 frames

// cos/sin(2*pi*j/32), j=0..15  (FFT-32 twiddles, e^{-2pi i j/32} = c - i*s)
constexpr float W32C[16] = {
    1.0f, 0.980785280403230f, 0.923879532511287f, 0.831469612302545f,
    0.707106781186548f, 0.555570233019602f, 0.382683432365090f, 0.195090322016128f,
    0.0f, -0.195090322016128f, -0.382683432365090f, -0.555570233019602f,
    -0.707106781186548f, -0.831469612302545f, -0.923879532511287f, -0.980785280403230f};
constexpr float W32S[16] = {
    0.0f, 0.195090322016128f, 0.382683432365090f, 0.555570233019602f,
    0.707106781186548f, 0.831469612302545f, 0.923879532511287f, 0.980785280403230f,
    1.0f, 0.980785280403230f, 0.923879532511287f, 0.831469612302545f,
    0.707106781186548f, 0.555570233019602f, 0.382683432365090f, 0.195090322016128f};

// cos/sin(2*pi*k/64), k=0..32 (recon twiddles e^{-2pi i k/64} = TC - i*TS; also Hann table)
constexpr float TC[33] = {
    1.0f, 0.995184726672197f, 0.980785280403230f, 0.956940335732209f,
    0.923879532511287f, 0.881921264348355f, 0.831469612302545f, 0.773010453362737f,
    0.707106781186548f, 0.634393284163645f, 0.555570233019602f, 0.471396736825998f,
    0.382683432365090f, 0.290284677254462f, 0.195090322016128f, 0.098017140329561f,
    0.0f, -0.098017140329561f, -0.195090322016128f, -0.290284677254462f,
    -0.382683432365090f, -0.471396736825998f, -0.555570233019602f, -0.634393284163645f,
    -0.707106781186548f, -0.773010453362737f, -0.831469612302545f, -0.881921264348355f,
    -0.923879532511287f, -0.956940335732209f, -0.980785280403230f, -0.995184726672197f,
    -1.0f};
constexpr float TS[33] = {
    0.0f, 0.098017140329561f, 0.195090322016128f, 0.290284677254462f,
    0.382683432365090f, 0.471396736825998f, 0.555570233019602f, 0.634393284163645f,
    0.707106781186548f, 0.773010453362737f, 0.831469612302545f, 0.881921264348355f,
    0.923879532511287f, 0.956940335732209f, 0.980785280403230f, 0.995184726672197f,
    1.0f, 0.995184726672197f, 0.980785280403230f, 0.956940335732209f,
    0.923879532511287f, 0.881921264348355f, 0.831469612302545f, 0.773010453362737f,
    0.707106781186548f, 0.634393284163645f, 0.555570233019602f, 0.471396736825998f,
    0.382683432365090f, 0.290284677254462f, 0.195090322016128f, 0.098017140329561f};

// 5-bit bit reversal (involution)
constexpr int BR32[32] = {0, 16, 8, 24, 4, 20, 12, 28, 2, 18, 10, 26, 6, 22, 14, 30,
                          1, 17, 9, 25, 5, 21, 13, 29, 3, 19, 11, 27, 7, 23, 15, 31};

// periodic Hann: w[n] = 0.5*(1 - cos(2*pi*n/64)); n is compile-time -> folds to a literal
__device__ __forceinline__ constexpr float hann(int n) {
    return 0.5f * (1.0f - TC[(n <= 32) ? n : (64 - n)]);
}

__global__ __launch_bounds__(BLOCK_THREADS)
void SpectralTokenizer_36103495090536_kernel(const float* __restrict__ in,
                                             float* __restrict__ out,
                                             int nrows) {
    __shared__ float so[ROWS_PER_BLOCK * OUT_PER_ROW];  // 42,240 B

    const int tid = threadIdx.x;
    const int row_local = tid / 5;
    const int frame = tid - row_local * 5;
    const long long row = (long long)blockIdx.x * ROWS_PER_BLOCK + row_local;
    const bool active = (row < (long long)nrows);

    float ar[32], ai[32];

    if (active) {
        // Load 64 windowed samples as 16 aligned float4s, pack directly into
        // bit-reversed complex slots: a[br(n)] = (x[2n]*w, x[2n+1]*w)
        const float4* src = (const float4*)(in + row * ROW_LEN + frame * 8);
#pragma unroll
        for (int i = 0; i < 16; i++) {
            float4 v = src[i];
            const int n0 = 2 * i, n1 = 2 * i + 1;
            const int p0 = BR32[n0], p1 = BR32[n1];
            ar[p0] = v.x * hann(4 * i + 0);
            ai[p0] = v.y * hann(4 * i + 1);
            ar[p1] = v.z * hann(4 * i + 2);
            ai[p1] = v.w * hann(4 * i + 3);
        }

#define BUTTERFLY(i0, i1, c, sn)                                   \
        {                                                          \
            float tr = (c) * ar[i1] + (sn) * ai[i1];               \
            float ti = (c) * ai[i1] - (sn) * ar[i1];               \
            float ur = ar[i0], ui = ai[i0];                        \
            ar[i0] = ur + tr; ai[i0] = ui + ti;                    \
            ar[i1] = ur - tr; ai[i1] = ui - ti;                    \
        }

        // Stage 1 (m=2): twiddle = 1
#pragma unroll
        for (int t = 0; t < 16; t++) BUTTERFLY(2 * t, 2 * t + 1, 1.0f, 0.0f);
        // Stage 2 (m=4): j=0 -> 1 ; j=1 -> -i
#pragma unroll
        for (int t = 0; t < 8; t++) {
            const int k = 4 * t;
            BUTTERFLY(k + 0, k + 2, 1.0f, 0.0f);
            BUTTERFLY(k + 1, k + 3, 0.0f, 1.0f);
        }
        // Stage 3 (m=8): j*4
#pragma unroll
        for (int t = 0; t < 4; t++) {
            const int k = 8 * t;
            BUTTERFLY(k + 0, k + 4, 1.0f, 0.0f);
            BUTTERFLY(k + 1, k + 5, W32C[4], W32S[4]);
            BUTTERFLY(k + 2, k + 6, 0.0f, 1.0f);
            BUTTERFLY(k + 3, k + 7, W32C[12], W32S[12]);
        }
        // Stage 4 (m=16): j*2
#pragma unroll
        for (int t = 0; t < 2; t++) {
            const int k = 16 * t;
#pragma unroll
            for (int j = 0; j < 8; j++) BUTTERFLY(k + j, k + j + 8, W32C[2 * j], W32S[2 * j]);
        }
        // Stage 5 (m=32): j
#pragma unroll
        for (int j = 0; j < 16; j++) BUTTERFLY(j, j + 16, W32C[j], W32S[j]);
#undef BUTTERFLY

        // Real-FFT reconstruction, magnitude, log1p; write freq-major into LDS.
        // LDS bank = (tid + 5k) mod 32 -> only 2-way lane-32 aliasing (free).
        float* orow = so + row_local * OUT_PER_ROW + frame;
#pragma unroll
        for (int k = 0; k <= 32; k++) {
            const int km = k & 31;
            const int kc = (32 - k) & 31;
            const float er = 0.5f * (ar[km] + ar[kc]);
            const float ei = 0.5f * (ai[km] - ai[kc]);
            const float pr = 0.5f * (ai[km] + ai[kc]);
            const float pi = 0.5f * (ar[kc] - ar[km]);
            const float xr = er + TC[k] * pr + TS[k] * pi;
            const float xi = ei + TC[k] * pi - TS[k] * pr;
            const float mag = sqrtf(xr * xr + xi * xi);
            orow[k * 5] = __logf(1.0f + mag);
        }
    }

    __syncthreads();

    // Block-contiguous coalesced store: 64 rows * 165 floats = 2640 float4s.
    const long long block_base = (long long)blockIdx.x * (ROWS_PER_BLOCK * OUT_PER_ROW);
    const long long total_out = (long long)nrows * OUT_PER_ROW;
    float4* dst = (float4*)(out + block_base);
    const float4* s4 = (const float4*)so;
    for (int t = tid; t < (ROWS_PER_BLOCK * OUT_PER_ROW / 4); t += BLOCK_THREADS) {
        if (block_base + 4 * t + 3 < total_out) dst[t] = s4[t];
    }
}

extern "C" void kernel_launch(void* const* d_in, const int* in_sizes, int n_in,
                              void* d_out, int out_size, void* d_ws, size_t ws_size,
                              hipStream_t stream) {
    const float* in = (const float*)d_in[0];
    float* out = (float*)d_out;
    const int nrows = in_sizes[0] / ROW_LEN;                       // 262144
    const int grid = (nrows + ROWS_PER_BLOCK - 1) / ROWS_PER_BLOCK; // 4096
    hipLaunchKernelGGL(SpectralTokenizer_36103495090536_kernel,
                       dim3(grid), dim3(BLOCK_THREADS), 0, stream, in, out, nrows);
}

// Round 2
// 266.698 us; speedup vs baseline: 1.0165x; 1.0165x over previous
//
#include <hip/hip_runtime.h>
#include <math.h>

// SpectralTokenizer: 262144 rows x 100 fp32 -> per row 5 frames (hop 8, len 64),
// Hann window, rfft-64, log1p(|.|), freq-major flatten -> 165 fp32 per row.
//
// R1 -> R2: VGPR_Count=56 with 64 live floats/thread proved the allocator was
// spilling FFT state to AGPRs (VALU inflated ~3x, no mem traffic). Pin budget
// with __launch_bounds__(320,2); fold 0.5 even/odd factor into the window.

#define ROWS_PER_BLOCK 64
#define BLOCK_THREADS (ROWS_PER_BLOCK * 5)   // 320 = 5 waves
#define ROW_LEN 100
#define OUT_PER_ROW 165                      // 33 freq * 5 frames

// cos/sin(2*pi*j/32), j=0..15  (FFT-32 twiddles, e^{-2pi i j/32} = c - i*s)
constexpr float W32C[16] = {
    1.0f, 0.980785280403230f, 0.923879532511287f, 0.831469612302545f,
    0.707106781186548f, 0.555570233019602f, 0.382683432365090f, 0.195090322016128f,
    0.0f, -0.195090322016128f, -0.382683432365090f, -0.555570233019602f,
    -0.707106781186548f, -0.831469612302545f, -0.923879532511287f, -0.980785280403230f};
constexpr float W32S[16] = {
    0.0f, 0.195090322016128f, 0.382683432365090f, 0.555570233019602f,
    0.707106781186548f, 0.831469612302545f, 0.923879532511287f, 0.980785280403230f,
    1.0f, 0.980785280403230f, 0.923879532511287f, 0.831469612302545f,
    0.707106781186548f, 0.555570233019602f, 0.382683432365090f, 0.195090322016128f};

// cos/sin(2*pi*k/64), k=0..32 (recon twiddles e^{-2pi i k/64} = TC - i*TS; also Hann table)
constexpr float TC[33] = {
    1.0f, 0.995184726672197f, 0.980785280403230f, 0.956940335732209f,
    0.923879532511287f, 0.881921264348355f, 0.831469612302545f, 0.773010453362737f,
    0.707106781186548f, 0.634393284163645f, 0.555570233019602f, 0.471396736825998f,
    0.382683432365090f, 0.290284677254462f, 0.195090322016128f, 0.098017140329561f,
    0.0f, -0.098017140329561f, -0.195090322016128f, -0.290284677254462f,
    -0.382683432365090f, -0.471396736825998f, -0.555570233019602f, -0.634393284163645f,
    -0.707106781186548f, -0.773010453362737f, -0.831469612302545f, -0.881921264348355f,
    -0.923879532511287f, -0.956940335732209f, -0.980785280403230f, -0.995184726672197f,
    -1.0f};
constexpr float TS[33] = {
    0.0f, 0.098017140329561f, 0.195090322016128f, 0.290284677254462f,
    0.382683432365090f, 0.471396736825998f, 0.555570233019602f, 0.634393284163645f,
    0.707106781186548f, 0.773010453362737f, 0.831469612302545f, 0.881921264348355f,
    0.923879532511287f, 0.956940335732209f, 0.980785280403230f, 0.995184726672197f,
    1.0f, 0.995184726672197f, 0.980785280403230f, 0.956940335732209f,
    0.923879532511287f, 0.881921264348355f, 0.831469612302545f, 0.773010453362737f,
    0.707106781186548f, 0.634393284163645f, 0.555570233019602f, 0.471396736825998f,
    0.382683432365090f, 0.290284677254462f, 0.195090322016128f, 0.098017140329561f};

// 5-bit bit reversal (involution)
constexpr int BR32[32] = {0, 16, 8, 24, 4, 20, 12, 28, 2, 18, 10, 26, 6, 22, 14, 30,
                          1, 17, 9, 25, 5, 21, 13, 29, 3, 19, 11, 27, 7, 23, 15, 31};

// periodic Hann scaled by 0.5 (the even/odd extraction factor folded in):
// w[n] = 0.25*(1 - cos(2*pi*n/64)); n compile-time -> folds to a literal
__device__ __forceinline__ constexpr float hann_half(int n) {
    return 0.25f * (1.0f - TC[(n <= 32) ? n : (64 - n)]);
}

__global__ __launch_bounds__(BLOCK_THREADS, 2)   // min 2 waves/EU -> VGPR cap 256, no spills
void SpectralTokenizer_36103495090536_kernel(const float* __restrict__ in,
                                             float* __restrict__ out,
                                             int nrows) {
    __shared__ float so[ROWS_PER_BLOCK * OUT_PER_ROW];  // 42,240 B -> 3 blocks/CU

    const int tid = threadIdx.x;
    const int row_local = tid / 5;
    const int frame = tid - row_local * 5;
    const long long row = (long long)blockIdx.x * ROWS_PER_BLOCK + row_local;
    const bool active = (row < (long long)nrows);

    float ar[32], ai[32];

    if (active) {
        // Load 64 windowed samples as 16 aligned float4s, pack directly into
        // bit-reversed complex slots: a[br(n)] = (x[2n]*w/2, x[2n+1]*w/2)
        const float4* src = (const float4*)(in + row * ROW_LEN + frame * 8);
#pragma unroll
        for (int i = 0; i < 16; i++) {
            float4 v = src[i];
            const int p0 = BR32[2 * i], p1 = BR32[2 * i + 1];
            ar[p0] = v.x * hann_half(4 * i + 0);
            ai[p0] = v.y * hann_half(4 * i + 1);
            ar[p1] = v.z * hann_half(4 * i + 2);
            ai[p1] = v.w * hann_half(4 * i + 3);
        }

#define BUTTERFLY(i0, i1, c, sn)                                   \
        {                                                          \
            float tr = (c) * ar[i1] + (sn) * ai[i1];               \
            float ti = (c) * ai[i1] - (sn) * ar[i1];               \
            float ur = ar[i0], ui = ai[i0];                        \
            ar[i0] = ur + tr; ai[i0] = ui + ti;                    \
            ar[i1] = ur - tr; ai[i1] = ui - ti;                    \
        }

        // Stage 1 (m=2): twiddle = 1
#pragma unroll
        for (int t = 0; t < 16; t++) BUTTERFLY(2 * t, 2 * t + 1, 1.0f, 0.0f);
        // Stage 2 (m=4): j=0 -> 1 ; j=1 -> -i
#pragma unroll
        for (int t = 0; t < 8; t++) {
            const int k = 4 * t;
            BUTTERFLY(k + 0, k + 2, 1.0f, 0.0f);
            BUTTERFLY(k + 1, k + 3, 0.0f, 1.0f);
        }
        // Stage 3 (m=8): j*4
#pragma unroll
        for (int t = 0; t < 4; t++) {
            const int k = 8 * t;
            BUTTERFLY(k + 0, k + 4, 1.0f, 0.0f);
            BUTTERFLY(k + 1, k + 5, W32C[4], W32S[4]);
            BUTTERFLY(k + 2, k + 6, 0.0f, 1.0f);
            BUTTERFLY(k + 3, k + 7, W32C[12], W32S[12]);
        }
        // Stage 4 (m=16): j*2
#pragma unroll
        for (int t = 0; t < 2; t++) {
            const int k = 16 * t;
#pragma unroll
            for (int j = 0; j < 8; j++) BUTTERFLY(k + j, k + j + 8, W32C[2 * j], W32S[2 * j]);
        }
        // Stage 5 (m=32): j
#pragma unroll
        for (int j = 0; j < 16; j++) BUTTERFLY(j, j + 16, W32C[j], W32S[j]);
#undef BUTTERFLY

        // Real-FFT reconstruction (0.5 already folded into window), magnitude,
        // log1p; write freq-major into LDS. Bank = (tid + 5k) mod 32 -> only
        // the free lane-32 2-way alias.
        float* orow = so + row_local * OUT_PER_ROW + frame;
#pragma unroll
        for (int k = 0; k <= 32; k++) {
            const int km = k & 31;
            const int kc = (32 - k) & 31;
            const float er = ar[km] + ar[kc];
            const float ei = ai[km] - ai[kc];
            const float pr = ai[km] + ai[kc];
            const float pi = ar[kc] - ar[km];
            const float xr = er + TC[k] * pr + TS[k] * pi;
            const float xi = ei + TC[k] * pi - TS[k] * pr;
            const float mag = sqrtf(xr * xr + xi * xi);
            orow[k * 5] = __logf(1.0f + mag);
        }
    }

    __syncthreads();

    // Block-contiguous coalesced store: 64 rows * 165 floats = 2640 float4s.
    const long long block_base = (long long)blockIdx.x * (ROWS_PER_BLOCK * OUT_PER_ROW);
    const long long total_out = (long long)nrows * OUT_PER_ROW;
    float4* dst = (float4*)(out + block_base);
    const float4* s4 = (const float4*)so;
#pragma unroll 2
    for (int t = tid; t < (ROWS_PER_BLOCK * OUT_PER_ROW / 4); t += BLOCK_THREADS) {
        if (block_base + 4 * t + 3 < total_out) dst[t] = s4[t];
    }
}

extern "C" void kernel_launch(void* const* d_in, const int* in_sizes, int n_in,
                              void* d_out, int out_size, void* d_ws, size_t ws_size,
                              hipStream_t stream) {
    const float* in = (const float*)d_in[0];
    float* out = (float*)d_out;
    const int nrows = in_sizes[0] / ROW_LEN;                        // 262144
    const int grid = (nrows + ROWS_PER_BLOCK - 1) / ROWS_PER_BLOCK; // 4096
    hipLaunchKernelGGL(SpectralTokenizer_36103495090536_kernel,
                       dim3(grid), dim3(BLOCK_THREADS), 0, stream, in, out, nrows);
}